// Round 1
// baseline (9412.860 us; speedup 1.0000x reference)
//
#include <hip/hip_runtime.h>

#define N_NODES 100000
#define N_EDGES 1600000
#define F_IN    256
#define F1      64     // H1*C1
#define H1      8
#define C1      8
#define F2      32
#define SLOPE   0.2f

// ---------------------------------------------------------------------------
// K1: h1 = x @ W1 (fp32), fused s1/d1 attention projections.
// W1 (256x64 = 64KB) staged in LDS; reads are wave-uniform -> broadcast.
// One node per thread; 64 fp32 accumulators.
// ---------------------------------------------------------------------------
__global__ __launch_bounds__(256) void k_gemm1(
        const float* __restrict__ x, const float* __restrict__ W1,
        const float* __restrict__ as1, const float* __restrict__ ad1,
        float* __restrict__ h1, float* __restrict__ s1, float* __restrict__ d1) {
    __shared__ float sW[F_IN * F1];          // 64 KB -> 2 blocks/CU
    const int tid = threadIdx.x;
    const float4* W4 = (const float4*)W1;
    float4* sW4 = (float4*)sW;
#pragma unroll
    for (int i = 0; i < (F_IN * F1 / 4) / 256; ++i)   // 16 iters
        sW4[i * 256 + tid] = W4[i * 256 + tid];
    __syncthreads();

    const int n = blockIdx.x * 256 + tid;
    if (n >= N_NODES) return;

    float acc[F1];
#pragma unroll
    for (int j = 0; j < F1; ++j) acc[j] = 0.f;

    const float4* x4 = (const float4*)(x + (size_t)n * F_IN);
    for (int kc = 0; kc < F_IN / 4; ++kc) {
        float4 xv = x4[kc];
        float xs[4] = {xv.x, xv.y, xv.z, xv.w};
#pragma unroll
        for (int kk = 0; kk < 4; ++kk) {
            const float4* wr = (const float4*)(sW + (kc * 4 + kk) * F1);
            float t = xs[kk];
#pragma unroll
            for (int j4 = 0; j4 < F1 / 4; ++j4) {
                float4 w = wr[j4];
                acc[j4 * 4 + 0] += t * w.x;
                acc[j4 * 4 + 1] += t * w.y;
                acc[j4 * 4 + 2] += t * w.z;
                acc[j4 * 4 + 3] += t * w.w;
            }
        }
    }

    float4* h4 = (float4*)(h1 + (size_t)n * F1);
#pragma unroll
    for (int j4 = 0; j4 < F1 / 4; ++j4)
        h4[j4] = make_float4(acc[j4 * 4 + 0], acc[j4 * 4 + 1],
                             acc[j4 * 4 + 2], acc[j4 * 4 + 3]);

#pragma unroll
    for (int h = 0; h < H1; ++h) {
        float s = 0.f, d = 0.f;
#pragma unroll
        for (int c = 0; c < C1; ++c) {
            s += acc[h * C1 + c] * as1[h * C1 + c];   // uniform -> scalar-cached
            d += acc[h * C1 + c] * ad1[h * C1 + c];
        }
        s1[(size_t)n * H1 + h] = s;
        d1[(size_t)n * H1 + h] = d;
    }
}

// ---------------------------------------------------------------------------
// K2: edge pass layer 1. Unshifted segment softmax (max-pass elided; |e|<~2
// by construction so exp() is safe; alpha = ex/z is shift-invariant).
// Accumulates z1[dst,h] and unnormalized agg1[dst,h,c] via f32 atomics.
// ---------------------------------------------------------------------------
__global__ __launch_bounds__(256) void k_edge1(
        const int* __restrict__ ei, const float* __restrict__ h1,
        const float* __restrict__ s1, const float* __restrict__ d1,
        float* __restrict__ z1, float* __restrict__ agg1) {
    const int e = blockIdx.x * 256 + threadIdx.x;
    if (e >= N_EDGES + N_NODES) return;
    int si, di;
    if (e < N_EDGES) { si = ei[e]; di = ei[N_EDGES + e]; }
    else             { si = di = e - N_EDGES; }           // self loop

    const float4* sv = (const float4*)(s1 + (size_t)si * H1);
    const float4* dv = (const float4*)(d1 + (size_t)di * H1);
    float4 sa = sv[0], sb = sv[1], da = dv[0], db = dv[1];
    float ev[H1] = {sa.x + da.x, sa.y + da.y, sa.z + da.z, sa.w + da.w,
                    sb.x + db.x, sb.y + db.y, sb.z + db.z, sb.w + db.w};
    float ex[H1];
#pragma unroll
    for (int h = 0; h < H1; ++h) {
        float v = ev[h];
        v = v > 0.f ? v : SLOPE * v;
        ex[h] = __expf(v);
        atomicAdd(z1 + (size_t)di * H1 + h, ex[h]);
    }
    const float4* hs = (const float4*)(h1 + (size_t)si * F1);
    float* ad = agg1 + (size_t)di * F1;
#pragma unroll
    for (int q = 0; q < F1 / 4; ++q) {      // head of feature q*4 is q/2
        float4 hv = hs[q];
        float w = ex[q / 2];
        atomicAdd(ad + q * 4 + 0, w * hv.x);
        atomicAdd(ad + q * 4 + 1, w * hv.y);
        atomicAdd(ad + q * 4 + 2, w * hv.z);
        atomicAdd(ad + q * 4 + 3, w * hv.w);
    }
}

// ---------------------------------------------------------------------------
// K3: x2 = elu(agg1/z1 + b1) in registers; fused h2 = x2 @ W2 (W2 in LDS);
// fused s2/d2. x2 never materialized.
// ---------------------------------------------------------------------------
__global__ __launch_bounds__(256) void k_node1(
        const float* __restrict__ agg1, const float* __restrict__ z1,
        const float* __restrict__ b1, const float* __restrict__ W2,
        const float* __restrict__ as2, const float* __restrict__ ad2,
        float* __restrict__ h2, float* __restrict__ s2, float* __restrict__ d2) {
    __shared__ float sW[F1 * F2];           // 8 KB
    const int tid = threadIdx.x;
    const float4* W4 = (const float4*)W2;
    float4* sW4 = (float4*)sW;
#pragma unroll
    for (int i = 0; i < (F1 * F2 / 4) / 256; ++i)   // 2 iters
        sW4[i * 256 + tid] = W4[i * 256 + tid];
    __syncthreads();

    const int n = blockIdx.x * 256 + tid;
    if (n >= N_NODES) return;

    float acc[F2];
#pragma unroll
    for (int c = 0; c < F2; ++c) acc[c] = 0.f;

    const float4* av = (const float4*)(agg1 + (size_t)n * F1);
    const float* zv = z1 + (size_t)n * H1;
#pragma unroll
    for (int q = 0; q < F1 / 4; ++q) {
        float4 a = av[q];
        float zi = 1.f / (zv[q / 2] + 1e-16f);
        float xv[4] = {a.x * zi + b1[q * 4 + 0], a.y * zi + b1[q * 4 + 1],
                       a.z * zi + b1[q * 4 + 2], a.w * zi + b1[q * 4 + 3]};
#pragma unroll
        for (int kk = 0; kk < 4; ++kk) {
            float t = xv[kk];
            t = t > 0.f ? t : __expf(t) - 1.f;          // elu
            const float4* wr = (const float4*)(sW + (q * 4 + kk) * F2);
#pragma unroll
            for (int c4 = 0; c4 < F2 / 4; ++c4) {
                float4 w = wr[c4];
                acc[c4 * 4 + 0] += t * w.x;
                acc[c4 * 4 + 1] += t * w.y;
                acc[c4 * 4 + 2] += t * w.z;
                acc[c4 * 4 + 3] += t * w.w;
            }
        }
    }

    float4* h4 = (float4*)(h2 + (size_t)n * F2);
#pragma unroll
    for (int c4 = 0; c4 < F2 / 4; ++c4)
        h4[c4] = make_float4(acc[c4 * 4 + 0], acc[c4 * 4 + 1],
                             acc[c4 * 4 + 2], acc[c4 * 4 + 3]);
    float s = 0.f, d = 0.f;
#pragma unroll
    for (int c = 0; c < F2; ++c) { s += acc[c] * as2[c]; d += acc[c] * ad2[c]; }
    s2[n] = s;
    d2[n] = d;
}

// ---------------------------------------------------------------------------
// K4: edge pass layer 2 (1 head, 32 ch). Accumulates unnormalized agg
// directly into d_out.
// ---------------------------------------------------------------------------
__global__ __launch_bounds__(256) void k_edge2(
        const int* __restrict__ ei, const float* __restrict__ h2,
        const float* __restrict__ s2, const float* __restrict__ d2,
        float* __restrict__ z2, float* __restrict__ out) {
    const int e = blockIdx.x * 256 + threadIdx.x;
    if (e >= N_EDGES + N_NODES) return;
    int si, di;
    if (e < N_EDGES) { si = ei[e]; di = ei[N_EDGES + e]; }
    else             { si = di = e - N_EDGES; }

    float v = s2[si] + d2[di];
    v = v > 0.f ? v : SLOPE * v;
    float ex = __expf(v);
    atomicAdd(z2 + di, ex);

    const float4* hs = (const float4*)(h2 + (size_t)si * F2);
    float* od = out + (size_t)di * F2;
#pragma unroll
    for (int q = 0; q < F2 / 4; ++q) {
        float4 hv = hs[q];
        atomicAdd(od + q * 4 + 0, ex * hv.x);
        atomicAdd(od + q * 4 + 1, ex * hv.y);
        atomicAdd(od + q * 4 + 2, ex * hv.z);
        atomicAdd(od + q * 4 + 3, ex * hv.w);
    }
}

// ---------------------------------------------------------------------------
// K5: out = log_softmax(agg2/z2 + b2), in place over d_out.
// ---------------------------------------------------------------------------
__global__ __launch_bounds__(256) void k_final(
        float* __restrict__ out, const float* __restrict__ z2,
        const float* __restrict__ b2) {
    const int n = blockIdx.x * 256 + threadIdx.x;
    if (n >= N_NODES) return;
    float zi = 1.f / (z2[n] + 1e-16f);
    float v[F2];
    float4* o4 = (float4*)(out + (size_t)n * F2);
#pragma unroll
    for (int q = 0; q < F2 / 4; ++q) {
        float4 a = o4[q];
        v[q * 4 + 0] = a.x * zi + b2[q * 4 + 0];
        v[q * 4 + 1] = a.y * zi + b2[q * 4 + 1];
        v[q * 4 + 2] = a.z * zi + b2[q * 4 + 2];
        v[q * 4 + 3] = a.w * zi + b2[q * 4 + 3];
    }
    float m = -1e30f;
#pragma unroll
    for (int c = 0; c < F2; ++c) m = fmaxf(m, v[c]);
    float ssum = 0.f;
#pragma unroll
    for (int c = 0; c < F2; ++c) ssum += __expf(v[c] - m);
    float lse = m + __logf(ssum);
#pragma unroll
    for (int q = 0; q < F2 / 4; ++q)
        o4[q] = make_float4(v[q * 4 + 0] - lse, v[q * 4 + 1] - lse,
                            v[q * 4 + 2] - lse, v[q * 4 + 3] - lse);
}

extern "C" void kernel_launch(void* const* d_in, const int* in_sizes, int n_in,
                              void* d_out, int out_size, void* d_ws, size_t ws_size,
                              hipStream_t stream) {
    const float* x   = (const float*)d_in[0];
    const int*   ei  = (const int*)d_in[1];
    const float* W1  = (const float*)d_in[2];
    const float* as1 = (const float*)d_in[3];
    const float* ad1 = (const float*)d_in[4];
    const float* b1  = (const float*)d_in[5];
    const float* W2  = (const float*)d_in[6];
    const float* as2 = (const float*)d_in[7];
    const float* ad2 = (const float*)d_in[8];
    const float* b2  = (const float*)d_in[9];
    float* out = (float*)d_out;

    // Workspace layout (fp32): 100k * 187 floats = 74.8 MB
    float* ws   = (float*)d_ws;
    float* h1   = ws;                              // N*64
    float* s1   = h1   + (size_t)N_NODES * F1;     // N*8
    float* d1   = s1   + (size_t)N_NODES * H1;     // N*8
    float* z1   = d1   + (size_t)N_NODES * H1;     // N*8
    float* agg1 = z1   + (size_t)N_NODES * H1;     // N*64
    float* h2   = agg1 + (size_t)N_NODES * F1;     // N*32
    float* s2   = h2   + (size_t)N_NODES * F2;     // N
    float* d2   = s2   + N_NODES;                  // N
    float* z2   = d2   + N_NODES;                  // N

    hipMemsetAsync(z1,   0, (size_t)N_NODES * H1 * sizeof(float), stream);
    hipMemsetAsync(agg1, 0, (size_t)N_NODES * F1 * sizeof(float), stream);
    hipMemsetAsync(z2,   0, (size_t)N_NODES * sizeof(float), stream);
    hipMemsetAsync(out,  0, (size_t)N_NODES * F2 * sizeof(float), stream);

    const int nb_n = (N_NODES + 255) / 256;
    const int nb_e = (N_EDGES + N_NODES + 255) / 256;
    k_gemm1<<<nb_n, 256, 0, stream>>>(x, W1, as1, ad1, h1, s1, d1);
    k_edge1<<<nb_e, 256, 0, stream>>>(ei, h1, s1, d1, z1, agg1);
    k_node1<<<nb_n, 256, 0, stream>>>(agg1, z1, b1, W2, as2, ad2, h2, s2, d2);
    k_edge2<<<nb_e, 256, 0, stream>>>(ei, h2, s2, d2, z2, out);
    k_final<<<nb_n, 256, 0, stream>>>(out, z2, b2);
}

// Round 2
// 686.385 us; speedup vs baseline: 13.7137x; 13.7137x over previous
//
#include <hip/hip_runtime.h>

#define N_NODES 100000
#define N_EDGES 1600000
#define N_TOT   (N_EDGES + N_NODES)   // edges + self loops
#define F_IN    256
#define F1      64     // H1*C1
#define H1      8
#define C1      8
#define F2      32
#define SLOPE   0.2f
#define CHUNK   2048
#define NCH     ((N_NODES + CHUNK - 1) / CHUNK)   // 49

// ---------------------------------------------------------------------------
// K1: h1 = x @ W1 (fp32), fused s1/d1 attention projections.
// ---------------------------------------------------------------------------
__global__ __launch_bounds__(256) void k_gemm1(
        const float* __restrict__ x, const float* __restrict__ W1,
        const float* __restrict__ as1, const float* __restrict__ ad1,
        float* __restrict__ h1, float* __restrict__ s1, float* __restrict__ d1) {
    __shared__ float sW[F_IN * F1];          // 64 KB
    const int tid = threadIdx.x;
    const float4* W4 = (const float4*)W1;
    float4* sW4 = (float4*)sW;
#pragma unroll
    for (int i = 0; i < (F_IN * F1 / 4) / 256; ++i)
        sW4[i * 256 + tid] = W4[i * 256 + tid];
    __syncthreads();

    const int n = blockIdx.x * 256 + tid;
    if (n >= N_NODES) return;

    float acc[F1];
#pragma unroll
    for (int j = 0; j < F1; ++j) acc[j] = 0.f;

    const float4* x4 = (const float4*)(x + (size_t)n * F_IN);
    for (int kc = 0; kc < F_IN / 4; ++kc) {
        float4 xv = x4[kc];
        float xs[4] = {xv.x, xv.y, xv.z, xv.w};
#pragma unroll
        for (int kk = 0; kk < 4; ++kk) {
            const float4* wr = (const float4*)(sW + (kc * 4 + kk) * F1);
            float t = xs[kk];
#pragma unroll
            for (int j4 = 0; j4 < F1 / 4; ++j4) {
                float4 w = wr[j4];
                acc[j4 * 4 + 0] += t * w.x;
                acc[j4 * 4 + 1] += t * w.y;
                acc[j4 * 4 + 2] += t * w.z;
                acc[j4 * 4 + 3] += t * w.w;
            }
        }
    }

    float4* h4 = (float4*)(h1 + (size_t)n * F1);
#pragma unroll
    for (int j4 = 0; j4 < F1 / 4; ++j4)
        h4[j4] = make_float4(acc[j4 * 4 + 0], acc[j4 * 4 + 1],
                             acc[j4 * 4 + 2], acc[j4 * 4 + 3]);

#pragma unroll
    for (int h = 0; h < H1; ++h) {
        float s = 0.f, d = 0.f;
#pragma unroll
        for (int c = 0; c < C1; ++c) {
            s += acc[h * C1 + c] * as1[h * C1 + c];
            d += acc[h * C1 + c] * ad1[h * C1 + c];
        }
        s1[(size_t)n * H1 + h] = s;
        d1[(size_t)n * H1 + h] = d;
    }
}

// ---------------------------------------------------------------------------
// CSR build: histogram -> hierarchical exclusive scan -> scatter.
// Only ~3.4M int atomics (vs 122M f32 atomics in the old edge passes).
// ---------------------------------------------------------------------------
__global__ __launch_bounds__(256) void k_hist(
        const int* __restrict__ ei, int* __restrict__ cnt) {
    const int e = blockIdx.x * 256 + threadIdx.x;
    if (e >= N_TOT) return;
    const int di = (e < N_EDGES) ? ei[N_EDGES + e] : (e - N_EDGES);
    atomicAdd(cnt + di, 1);
}

__global__ __launch_bounds__(256) void k_scan_a(
        const int* __restrict__ cnt, int* __restrict__ row_ptr,
        int* __restrict__ bsum) {
    __shared__ int sdata[256];
    const int tid = threadIdx.x;
    const int base = blockIdx.x * CHUNK + tid * 8;
    int v[8];
    int tot = 0;
#pragma unroll
    for (int j = 0; j < 8; ++j) {
        v[j] = (base + j < N_NODES) ? cnt[base + j] : 0;
        tot += v[j];
    }
    sdata[tid] = tot;
    __syncthreads();
    for (int off = 1; off < 256; off <<= 1) {
        int t = (tid >= off) ? sdata[tid - off] : 0;
        __syncthreads();
        sdata[tid] += t;
        __syncthreads();
    }
    int run = sdata[tid] - tot;          // exclusive offset within chunk
#pragma unroll
    for (int j = 0; j < 8; ++j) {
        if (base + j < N_NODES) row_ptr[base + j] = run;
        run += v[j];
    }
    if (tid == 255) bsum[blockIdx.x] = sdata[255];
}

__global__ __launch_bounds__(64) void k_scan_b(int* __restrict__ bsum) {
    const int t = threadIdx.x;
    int v = (t < NCH) ? bsum[t] : 0;
    const int orig = v;
    for (int off = 1; off < 64; off <<= 1) {
        int u = __shfl_up(v, off);
        if (t >= off) v += u;
    }
    if (t < NCH) bsum[t] = v - orig;     // exclusive
}

__global__ __launch_bounds__(256) void k_scan_c(
        int* __restrict__ row_ptr, const int* __restrict__ bsum) {
    const int i = blockIdx.x * 256 + threadIdx.x;
    if (i < N_NODES) row_ptr[i] += bsum[i / CHUNK];
    else if (i == N_NODES) row_ptr[N_NODES] = N_TOT;
}

__global__ __launch_bounds__(256) void k_scatter(
        const int* __restrict__ ei, const int* __restrict__ row_ptr,
        int* __restrict__ tmp, int* __restrict__ srcs) {
    const int e = blockIdx.x * 256 + threadIdx.x;
    if (e >= N_TOT) return;
    int si, di;
    if (e < N_EDGES) { si = ei[e]; di = ei[N_EDGES + e]; }
    else             { si = di = e - N_EDGES; }
    const int pos = row_ptr[di] + atomicAdd(tmp + di, 1);
    srcs[pos] = si;
}

// ---------------------------------------------------------------------------
// K_agg1: one wave per dst node; lane = feature channel (head = lane>>3).
// Each lane redundantly accumulates its head's z = sum(exp) -> no reduction.
// Emits x2 = elu(agg/z + b1) directly.
// ---------------------------------------------------------------------------
__global__ __launch_bounds__(256) void k_agg1(
        const int* __restrict__ row_ptr, const int* __restrict__ srcs,
        const float* __restrict__ h1, const float* __restrict__ s1,
        const float* __restrict__ d1, const float* __restrict__ b1,
        float* __restrict__ x2) {
    const int wid = (blockIdx.x * 256 + threadIdx.x) >> 6;
    if (wid >= N_NODES) return;
    const int lane = threadIdx.x & 63;
    const int h = lane >> 3;
    const float dh = d1[(size_t)wid * H1 + h];
    const int beg = row_ptr[wid], end = row_ptr[wid + 1];
    float acc = 0.f, z = 0.f;
    for (int i = beg; i < end; ++i) {
        const int src = srcs[i];
        float e = s1[(size_t)src * H1 + h] + dh;
        e = e > 0.f ? e : SLOPE * e;
        const float ex = __expf(e);
        z += ex;
        acc += ex * h1[(size_t)src * F1 + lane];
    }
    float v = acc / (z + 1e-16f) + b1[lane];
    v = v > 0.f ? v : __expf(v) - 1.f;                 // elu
    x2[(size_t)wid * F1 + lane] = v;
}

// ---------------------------------------------------------------------------
// K_node1: h2 = x2 @ W2 (W2 in LDS), fused s2/d2.
// ---------------------------------------------------------------------------
__global__ __launch_bounds__(256) void k_node1(
        const float* __restrict__ x2, const float* __restrict__ W2,
        const float* __restrict__ as2, const float* __restrict__ ad2,
        float* __restrict__ h2, float* __restrict__ s2, float* __restrict__ d2) {
    __shared__ float sW[F1 * F2];           // 8 KB
    const int tid = threadIdx.x;
    const float4* W4 = (const float4*)W2;
    float4* sW4 = (float4*)sW;
#pragma unroll
    for (int i = 0; i < (F1 * F2 / 4) / 256; ++i)
        sW4[i * 256 + tid] = W4[i * 256 + tid];
    __syncthreads();

    const int n = blockIdx.x * 256 + tid;
    if (n >= N_NODES) return;

    float acc[F2];
#pragma unroll
    for (int c = 0; c < F2; ++c) acc[c] = 0.f;

    const float4* xv4 = (const float4*)(x2 + (size_t)n * F1);
#pragma unroll
    for (int q = 0; q < F1 / 4; ++q) {
        float4 a = xv4[q];
        float xv[4] = {a.x, a.y, a.z, a.w};
#pragma unroll
        for (int kk = 0; kk < 4; ++kk) {
            float t = xv[kk];
            const float4* wr = (const float4*)(sW + (q * 4 + kk) * F2);
#pragma unroll
            for (int c4 = 0; c4 < F2 / 4; ++c4) {
                float4 w = wr[c4];
                acc[c4 * 4 + 0] += t * w.x;
                acc[c4 * 4 + 1] += t * w.y;
                acc[c4 * 4 + 2] += t * w.z;
                acc[c4 * 4 + 3] += t * w.w;
            }
        }
    }

    float4* h4 = (float4*)(h2 + (size_t)n * F2);
#pragma unroll
    for (int c4 = 0; c4 < F2 / 4; ++c4)
        h4[c4] = make_float4(acc[c4 * 4 + 0], acc[c4 * 4 + 1],
                             acc[c4 * 4 + 2], acc[c4 * 4 + 3]);
    float s = 0.f, d = 0.f;
#pragma unroll
    for (int c = 0; c < F2; ++c) { s += acc[c] * as2[c]; d += acc[c] * ad2[c]; }
    s2[n] = s;
    d2[n] = d;
}

// ---------------------------------------------------------------------------
// K_agg2: one wave per dst; 32 lanes = channels, 2 edges per iteration.
// Fused log_softmax via 32-lane shfl reductions. Writes d_out directly.
// ---------------------------------------------------------------------------
__global__ __launch_bounds__(256) void k_agg2(
        const int* __restrict__ row_ptr, const int* __restrict__ srcs,
        const float* __restrict__ h2, const float* __restrict__ s2,
        const float* __restrict__ d2, const float* __restrict__ b2,
        float* __restrict__ out) {
    const int wid = (blockIdx.x * 256 + threadIdx.x) >> 6;
    if (wid >= N_NODES) return;
    const int lane = threadIdx.x & 63;
    const int half = lane >> 5;
    const int c = lane & 31;
    const float dn = d2[wid];
    const int beg = row_ptr[wid], end = row_ptr[wid + 1];
    float acc = 0.f, z = 0.f;
    for (int i = beg + half; i < end; i += 2) {
        const int src = srcs[i];
        float e = s2[src] + dn;
        e = e > 0.f ? e : SLOPE * e;
        const float ex = __expf(e);
        z += ex;
        acc += ex * h2[(size_t)src * F2 + c];
    }
    acc += __shfl_xor(acc, 32);
    z   += __shfl_xor(z, 32);
    float v = acc / (z + 1e-16f) + b2[c];
    // log_softmax over the 32 channels (intra-32-lane group reductions)
    float m = v;
#pragma unroll
    for (int off = 16; off >= 1; off >>= 1) m = fmaxf(m, __shfl_xor(m, off));
    float ssum = __expf(v - m);
#pragma unroll
    for (int off = 16; off >= 1; off >>= 1) ssum += __shfl_xor(ssum, off);
    const float lse = m + __logf(ssum);
    if (half == 0) out[(size_t)wid * F2 + c] = v - lse;
}

extern "C" void kernel_launch(void* const* d_in, const int* in_sizes, int n_in,
                              void* d_out, int out_size, void* d_ws, size_t ws_size,
                              hipStream_t stream) {
    const float* x   = (const float*)d_in[0];
    const int*   ei  = (const int*)d_in[1];
    const float* W1  = (const float*)d_in[2];
    const float* as1 = (const float*)d_in[3];
    const float* ad1 = (const float*)d_in[4];
    const float* b1  = (const float*)d_in[5];
    const float* W2  = (const float*)d_in[6];
    const float* as2 = (const float*)d_in[7];
    const float* ad2 = (const float*)d_in[8];
    const float* b2  = (const float*)d_in[9];
    float* out = (float*)d_out;

    // Workspace layout
    float* ws   = (float*)d_ws;
    float* h1   = ws;                              // N*64
    float* s1   = h1   + (size_t)N_NODES * F1;     // N*8
    float* d1   = s1   + (size_t)N_NODES * H1;     // N*8
    float* x2   = d1   + (size_t)N_NODES * H1;     // N*64
    float* h2   = x2   + (size_t)N_NODES * F1;     // N*32
    float* s2   = h2   + (size_t)N_NODES * F2;     // N
    float* d2   = s2   + N_NODES;                  // N
    int* cnt     = (int*)(d2 + N_NODES);           // N
    int* tmp     = cnt + N_NODES;                  // N
    int* row_ptr = tmp + N_NODES;                  // N+1
    int* bsum    = row_ptr + N_NODES + 1;          // 64
    int* srcs    = bsum + 64;                      // E+N

    hipMemsetAsync(cnt, 0, (size_t)N_NODES * sizeof(int), stream);
    hipMemsetAsync(tmp, 0, (size_t)N_NODES * sizeof(int), stream);

    const int nb_n = (N_NODES + 255) / 256;
    const int nb_e = (N_TOT + 255) / 256;
    const int nb_w = (N_NODES * 64 + 255) / 256;   // one wave per node

    k_gemm1<<<nb_n, 256, 0, stream>>>(x, W1, as1, ad1, h1, s1, d1);
    k_hist<<<nb_e, 256, 0, stream>>>(ei, cnt);
    k_scan_a<<<NCH, 256, 0, stream>>>(cnt, row_ptr, bsum);
    k_scan_b<<<1, 64, 0, stream>>>(bsum);
    k_scan_c<<<(N_NODES + 256) / 256, 256, 0, stream>>>(row_ptr, bsum);
    k_scatter<<<nb_e, 256, 0, stream>>>(ei, row_ptr, tmp, srcs);
    k_agg1<<<nb_w, 256, 0, stream>>>(row_ptr, srcs, h1, s1, d1, b1, x2);
    k_node1<<<nb_n, 256, 0, stream>>>(x2, W2, as2, ad2, h2, s2, d2);
    k_agg2<<<nb_w, 256, 0, stream>>>(row_ptr, srcs, h2, s2, d2, b2, out);
}

// Round 3
// 573.653 us; speedup vs baseline: 16.4086x; 1.1965x over previous
//
#include <hip/hip_runtime.h>

#define N_NODES 100000
#define N_EDGES 1600000
#define N_TOT   (N_EDGES + N_NODES)   // edges + self loops
#define F_IN    256
#define F1      64     // H1*C1
#define H1      8
#define C1      8
#define F2      32
#define SLOPE   0.2f
#define CHUNK   2048
#define NCH     ((N_NODES + CHUNK - 1) / CHUNK)   // 49

typedef unsigned int  uint;
typedef unsigned short ushort;

__device__ inline ushort f2bf(float f) {               // RNE float->bf16
    uint u = __float_as_uint(f);
    uint r = u + 0x7fffu + ((u >> 16) & 1u);
    return (ushort)(r >> 16);
}
__device__ inline float bflo(uint u) { return __uint_as_float(u << 16); }
__device__ inline float bfhi(uint u) { return __uint_as_float(u & 0xffff0000u); }

// ---------------------------------------------------------------------------
// K1: h1 = x @ W1 (fp32 math), h1 stored bf16-packed; fused s1/d1 projections.
// ---------------------------------------------------------------------------
__global__ __launch_bounds__(256) void k_gemm1(
        const float* __restrict__ x, const float* __restrict__ W1,
        const float* __restrict__ as1, const float* __restrict__ ad1,
        ushort* __restrict__ h1b, float* __restrict__ s1, float* __restrict__ d1) {
    __shared__ float sW[F_IN * F1];          // 64 KB
    const int tid = threadIdx.x;
    const float4* W4 = (const float4*)W1;
    float4* sW4 = (float4*)sW;
#pragma unroll
    for (int i = 0; i < (F_IN * F1 / 4) / 256; ++i)
        sW4[i * 256 + tid] = W4[i * 256 + tid];
    __syncthreads();

    const int n = blockIdx.x * 256 + tid;
    if (n >= N_NODES) return;

    float acc[F1];
#pragma unroll
    for (int j = 0; j < F1; ++j) acc[j] = 0.f;

    const float4* x4 = (const float4*)(x + (size_t)n * F_IN);
    for (int kc = 0; kc < F_IN / 4; ++kc) {
        float4 xv = x4[kc];
        float xs[4] = {xv.x, xv.y, xv.z, xv.w};
#pragma unroll
        for (int kk = 0; kk < 4; ++kk) {
            const float4* wr = (const float4*)(sW + (kc * 4 + kk) * F1);
            float t = xs[kk];
#pragma unroll
            for (int j4 = 0; j4 < F1 / 4; ++j4) {
                float4 w = wr[j4];
                acc[j4 * 4 + 0] += t * w.x;
                acc[j4 * 4 + 1] += t * w.y;
                acc[j4 * 4 + 2] += t * w.z;
                acc[j4 * 4 + 3] += t * w.w;
            }
        }
    }

    uint up[F1 / 2];
#pragma unroll
    for (int j = 0; j < F1 / 2; ++j)
        up[j] = (uint)f2bf(acc[2 * j]) | ((uint)f2bf(acc[2 * j + 1]) << 16);
    uint4* o4 = (uint4*)(h1b + (size_t)n * F1);
#pragma unroll
    for (int q = 0; q < F1 / 8; ++q)
        o4[q] = make_uint4(up[q * 4 + 0], up[q * 4 + 1], up[q * 4 + 2], up[q * 4 + 3]);

#pragma unroll
    for (int h = 0; h < H1; ++h) {
        float s = 0.f, d = 0.f;
#pragma unroll
        for (int c = 0; c < C1; ++c) {
            s += acc[h * C1 + c] * as1[h * C1 + c];
            d += acc[h * C1 + c] * ad1[h * C1 + c];
        }
        s1[(size_t)n * H1 + h] = s;
        d1[(size_t)n * H1 + h] = d;
    }
}

// ---------------------------------------------------------------------------
// CSR build: histogram -> hierarchical exclusive scan -> scatter.
// ---------------------------------------------------------------------------
__global__ __launch_bounds__(256) void k_hist(
        const int* __restrict__ ei, int* __restrict__ cnt) {
    const int e = blockIdx.x * 256 + threadIdx.x;
    if (e >= N_TOT) return;
    const int di = (e < N_EDGES) ? ei[N_EDGES + e] : (e - N_EDGES);
    atomicAdd(cnt + di, 1);
}

__global__ __launch_bounds__(256) void k_scan_a(
        const int* __restrict__ cnt, int* __restrict__ row_ptr,
        int* __restrict__ bsum) {
    __shared__ int sdata[256];
    const int tid = threadIdx.x;
    const int base = blockIdx.x * CHUNK + tid * 8;
    int v[8];
    int tot = 0;
#pragma unroll
    for (int j = 0; j < 8; ++j) {
        v[j] = (base + j < N_NODES) ? cnt[base + j] : 0;
        tot += v[j];
    }
    sdata[tid] = tot;
    __syncthreads();
    for (int off = 1; off < 256; off <<= 1) {
        int t = (tid >= off) ? sdata[tid - off] : 0;
        __syncthreads();
        sdata[tid] += t;
        __syncthreads();
    }
    int run = sdata[tid] - tot;
#pragma unroll
    for (int j = 0; j < 8; ++j) {
        if (base + j < N_NODES) row_ptr[base + j] = run;
        run += v[j];
    }
    if (tid == 255) bsum[blockIdx.x] = sdata[255];
}

__global__ __launch_bounds__(64) void k_scan_b(int* __restrict__ bsum) {
    const int t = threadIdx.x;
    int v = (t < NCH) ? bsum[t] : 0;
    const int orig = v;
    for (int off = 1; off < 64; off <<= 1) {
        int u = __shfl_up(v, off);
        if (t >= off) v += u;
    }
    if (t < NCH) bsum[t] = v - orig;
}

__global__ __launch_bounds__(256) void k_scan_c(
        int* __restrict__ row_ptr, const int* __restrict__ bsum) {
    const int i = blockIdx.x * 256 + threadIdx.x;
    if (i < N_NODES) row_ptr[i] += bsum[i / CHUNK];
    else if (i == N_NODES) row_ptr[N_NODES] = N_TOT;
}

__global__ __launch_bounds__(256) void k_scatter(
        const int* __restrict__ ei, const int* __restrict__ row_ptr,
        int* __restrict__ tmp, int* __restrict__ srcs) {
    const int e = blockIdx.x * 256 + threadIdx.x;
    if (e >= N_TOT) return;
    int si, di;
    if (e < N_EDGES) { si = ei[e]; di = ei[N_EDGES + e]; }
    else             { si = di = e - N_EDGES; }
    const int pos = row_ptr[di] + atomicAdd(tmp + di, 1);
    srcs[pos] = si;
}

// ---------------------------------------------------------------------------
// K_agg1: half-wave per edge (2 edges/wave-iter), unroll x2 (4 gathers in
// flight). Lane holds a bf16 channel pair. Emits x2 = elu(agg/z + b1) bf16.
// ---------------------------------------------------------------------------
__global__ __launch_bounds__(256) void k_agg1(
        const int* __restrict__ row_ptr, const int* __restrict__ srcs,
        const ushort* __restrict__ h1b, const float* __restrict__ s1,
        const float* __restrict__ d1, const float* __restrict__ b1,
        ushort* __restrict__ x2b) {
    const int wid = (blockIdx.x * 256 + threadIdx.x) >> 6;
    if (wid >= N_NODES) return;
    const int lane = threadIdx.x & 63;
    const int half = lane >> 5;
    const int c = lane & 31;          // channel pair index: channels 2c, 2c+1
    const int hd = c >> 2;            // head
    const float dh = d1[(size_t)wid * H1 + hd];
    const int beg = row_ptr[wid], end = row_ptr[wid + 1];
    const uint* hv = (const uint*)h1b;    // 32 uints per node
    float ax = 0.f, ay = 0.f, z = 0.f;
    int i = beg + half;
    for (; i + 2 < end; i += 4) {
        const int sA = srcs[i], sB = srcs[i + 2];
        float eA = s1[(size_t)sA * H1 + hd] + dh;
        float eB = s1[(size_t)sB * H1 + hd] + dh;
        eA = eA > 0.f ? eA : SLOPE * eA;
        eB = eB > 0.f ? eB : SLOPE * eB;
        const float xA = __expf(eA), xB = __expf(eB);
        const uint uA = hv[(size_t)sA * 32 + c];
        const uint uB = hv[(size_t)sB * 32 + c];
        z  += xA + xB;
        ax += xA * bflo(uA) + xB * bflo(uB);
        ay += xA * bfhi(uA) + xB * bfhi(uB);
    }
    for (; i < end; i += 2) {
        const int sA = srcs[i];
        float eA = s1[(size_t)sA * H1 + hd] + dh;
        eA = eA > 0.f ? eA : SLOPE * eA;
        const float xA = __expf(eA);
        const uint uA = hv[(size_t)sA * 32 + c];
        z  += xA;
        ax += xA * bflo(uA);
        ay += xA * bfhi(uA);
    }
    ax += __shfl_xor(ax, 32);
    ay += __shfl_xor(ay, 32);
    z  += __shfl_xor(z, 32);
    if (half == 0) {
        const float zi = 1.f / (z + 1e-16f);
        float v0 = ax * zi + b1[2 * c];
        float v1 = ay * zi + b1[2 * c + 1];
        v0 = v0 > 0.f ? v0 : __expf(v0) - 1.f;
        v1 = v1 > 0.f ? v1 : __expf(v1) - 1.f;
        ((uint*)x2b)[(size_t)wid * 32 + c] = (uint)f2bf(v0) | ((uint)f2bf(v1) << 16);
    }
}

// ---------------------------------------------------------------------------
// K_node1: h2 = x2 @ W2 (x2 bf16 in, h2 bf16 out, W2 in LDS), fused s2/d2.
// ---------------------------------------------------------------------------
__global__ __launch_bounds__(256) void k_node1(
        const ushort* __restrict__ x2b, const float* __restrict__ W2,
        const float* __restrict__ as2, const float* __restrict__ ad2,
        ushort* __restrict__ h2b, float* __restrict__ s2, float* __restrict__ d2) {
    __shared__ float sW[F1 * F2];           // 8 KB
    const int tid = threadIdx.x;
    const float4* W4 = (const float4*)W2;
    float4* sW4 = (float4*)sW;
#pragma unroll
    for (int i = 0; i < (F1 * F2 / 4) / 256; ++i)
        sW4[i * 256 + tid] = W4[i * 256 + tid];
    __syncthreads();

    const int n = blockIdx.x * 256 + tid;
    if (n >= N_NODES) return;

    float acc[F2];
#pragma unroll
    for (int c = 0; c < F2; ++c) acc[c] = 0.f;

    const uint4* xv4 = (const uint4*)(x2b + (size_t)n * F1);   // 8 loads
#pragma unroll
    for (int q = 0; q < 8; ++q) {
        uint4 u = xv4[q];
        float xs[8] = {bflo(u.x), bfhi(u.x), bflo(u.y), bfhi(u.y),
                       bflo(u.z), bfhi(u.z), bflo(u.w), bfhi(u.w)};
#pragma unroll
        for (int kk = 0; kk < 8; ++kk) {
            const float t = xs[kk];
            const float4* wr = (const float4*)(sW + (q * 8 + kk) * F2);
#pragma unroll
            for (int c4 = 0; c4 < F2 / 4; ++c4) {
                float4 w = wr[c4];
                acc[c4 * 4 + 0] += t * w.x;
                acc[c4 * 4 + 1] += t * w.y;
                acc[c4 * 4 + 2] += t * w.z;
                acc[c4 * 4 + 3] += t * w.w;
            }
        }
    }

    uint up[F2 / 2];
#pragma unroll
    for (int j = 0; j < F2 / 2; ++j)
        up[j] = (uint)f2bf(acc[2 * j]) | ((uint)f2bf(acc[2 * j + 1]) << 16);
    uint4* o4 = (uint4*)(h2b + (size_t)n * F2);
#pragma unroll
    for (int q = 0; q < F2 / 8; ++q)
        o4[q] = make_uint4(up[q * 4 + 0], up[q * 4 + 1], up[q * 4 + 2], up[q * 4 + 3]);

    float s = 0.f, d = 0.f;
#pragma unroll
    for (int c = 0; c < F2; ++c) { s += acc[c] * as2[c]; d += acc[c] * ad2[c]; }
    s2[n] = s;
    d2[n] = d;
}

// ---------------------------------------------------------------------------
// K_agg2: quarter-wave per edge (4 edges/wave-iter), unroll x2 (8 gathers in
// flight). Fused log_softmax (16-lane shfl). Writes d_out directly.
// ---------------------------------------------------------------------------
__global__ __launch_bounds__(256) void k_agg2(
        const int* __restrict__ row_ptr, const int* __restrict__ srcs,
        const ushort* __restrict__ h2b, const float* __restrict__ s2,
        const float* __restrict__ d2, const float* __restrict__ b2,
        float* __restrict__ out) {
    const int wid = (blockIdx.x * 256 + threadIdx.x) >> 6;
    if (wid >= N_NODES) return;
    const int lane = threadIdx.x & 63;
    const int q = lane >> 4;
    const int c = lane & 15;          // channel pair index: channels 2c, 2c+1
    const float dn = d2[wid];
    const int beg = row_ptr[wid], end = row_ptr[wid + 1];
    const uint* hv = (const uint*)h2b;    // 16 uints per node
    float ax = 0.f, ay = 0.f, z = 0.f;
    int i = beg + q;
    for (; i + 4 < end; i += 8) {
        const int sA = srcs[i], sB = srcs[i + 4];
        float eA = s2[sA] + dn;
        float eB = s2[sB] + dn;
        eA = eA > 0.f ? eA : SLOPE * eA;
        eB = eB > 0.f ? eB : SLOPE * eB;
        const float xA = __expf(eA), xB = __expf(eB);
        const uint uA = hv[(size_t)sA * 16 + c];
        const uint uB = hv[(size_t)sB * 16 + c];
        z  += xA + xB;
        ax += xA * bflo(uA) + xB * bflo(uB);
        ay += xA * bfhi(uA) + xB * bfhi(uB);
    }
    for (; i < end; i += 4) {
        const int sA = srcs[i];
        float eA = s2[sA] + dn;
        eA = eA > 0.f ? eA : SLOPE * eA;
        const float xA = __expf(eA);
        const uint uA = hv[(size_t)sA * 16 + c];
        z  += xA;
        ax += xA * bflo(uA);
        ay += xA * bfhi(uA);
    }
    ax += __shfl_xor(ax, 16); ax += __shfl_xor(ax, 32);
    ay += __shfl_xor(ay, 16); ay += __shfl_xor(ay, 32);
    z  += __shfl_xor(z, 16);  z  += __shfl_xor(z, 32);

    const float zi = 1.f / (z + 1e-16f);
    const float v0 = ax * zi + b2[2 * c];
    const float v1 = ay * zi + b2[2 * c + 1];
    float m = fmaxf(v0, v1);
#pragma unroll
    for (int off = 8; off >= 1; off >>= 1) m = fmaxf(m, __shfl_xor(m, off));
    float ssum = __expf(v0 - m) + __expf(v1 - m);
#pragma unroll
    for (int off = 8; off >= 1; off >>= 1) ssum += __shfl_xor(ssum, off);
    const float lse = m + __logf(ssum);
    if (lane < 16)
        ((float2*)out)[(size_t)wid * 16 + c] = make_float2(v0 - lse, v1 - lse);
}

extern "C" void kernel_launch(void* const* d_in, const int* in_sizes, int n_in,
                              void* d_out, int out_size, void* d_ws, size_t ws_size,
                              hipStream_t stream) {
    const float* x   = (const float*)d_in[0];
    const int*   ei  = (const int*)d_in[1];
    const float* W1  = (const float*)d_in[2];
    const float* as1 = (const float*)d_in[3];
    const float* ad1 = (const float*)d_in[4];
    const float* b1  = (const float*)d_in[5];
    const float* W2  = (const float*)d_in[6];
    const float* as2 = (const float*)d_in[7];
    const float* ad2 = (const float*)d_in[8];
    const float* b2  = (const float*)d_in[9];
    float* out = (float*)d_out;

    // Workspace: bf16 tables first (16B-aligned rows), then fp32, then ints.
    ushort* h1b = (ushort*)d_ws;                   // N*64 bf16
    ushort* x2b = h1b + (size_t)N_NODES * F1;      // N*64 bf16
    ushort* h2b = x2b + (size_t)N_NODES * F1;      // N*32 bf16
    float*  s1  = (float*)(h2b + (size_t)N_NODES * F2);  // N*8
    float*  d1  = s1 + (size_t)N_NODES * H1;       // N*8
    float*  s2  = d1 + (size_t)N_NODES * H1;       // N
    float*  d2  = s2 + N_NODES;                    // N
    int* cnt     = (int*)(d2 + N_NODES);           // N
    int* tmp     = cnt + N_NODES;                  // N
    int* row_ptr = tmp + N_NODES;                  // N+1
    int* bsum    = row_ptr + N_NODES + 1;          // 64
    int* srcs    = bsum + 64;                      // N_TOT

    hipMemsetAsync(cnt, 0, (size_t)N_NODES * sizeof(int), stream);
    hipMemsetAsync(tmp, 0, (size_t)N_NODES * sizeof(int), stream);

    const int nb_n = (N_NODES + 255) / 256;
    const int nb_e = (N_TOT + 255) / 256;
    const int nb_w = (N_NODES * 64 + 255) / 256;   // one wave per node

    k_gemm1<<<nb_n, 256, 0, stream>>>(x, W1, as1, ad1, h1b, s1, d1);
    k_hist<<<nb_e, 256, 0, stream>>>(ei, cnt);
    k_scan_a<<<NCH, 256, 0, stream>>>(cnt, row_ptr, bsum);
    k_scan_b<<<1, 64, 0, stream>>>(bsum);
    k_scan_c<<<(N_NODES + 256) / 256, 256, 0, stream>>>(row_ptr, bsum);
    k_scatter<<<nb_e, 256, 0, stream>>>(ei, row_ptr, tmp, srcs);
    k_agg1<<<nb_w, 256, 0, stream>>>(row_ptr, srcs, h1b, s1, d1, b1, x2b);
    k_node1<<<nb_n, 256, 0, stream>>>(x2b, W2, as2, ad2, h2b, s2, d2);
    k_agg2<<<nb_w, 256, 0, stream>>>(row_ptr, srcs, h2b, s2, d2, b2, out);
}

// Round 4
// 480.787 us; speedup vs baseline: 19.5780x; 1.1932x over previous
//
#include <hip/hip_runtime.h>
#include <hip/hip_bf16.h>

#define N_NODES 100000
#define N_EDGES 1600000
#define N_TOT   (N_EDGES + N_NODES)   // edges + self loops
#define F_IN    256
#define F1      64     // H1*C1
#define H1      8
#define C1      8
#define F2      32
#define SLOPE   0.2f
#define CHUNK   2048
#define NCH     ((N_NODES + CHUNK - 1) / CHUNK)   // 49

typedef unsigned int  uint;
typedef unsigned short ushort;
typedef __attribute__((ext_vector_type(8))) short bf16x8;
typedef __attribute__((ext_vector_type(4))) float f32x4;

__device__ inline ushort f2bf(float f) {               // RNE float->bf16
    uint u = __float_as_uint(f);
    uint r = u + 0x7fffu + ((u >> 16) & 1u);
    return (ushort)(r >> 16);
}
__device__ inline float bflo(uint u) { return __uint_as_float(u << 16); }
__device__ inline float bfhi(uint u) { return __uint_as_float(u & 0xffff0000u); }
__device__ inline uint pk2bf(float a, float b) {       // v_cvt_pk_bf16_f32
    __hip_bfloat162 h = __float22bfloat162_rn(make_float2(a, b));
    union { __hip_bfloat162 h; uint u; } cv; cv.h = h;
    return cv.u;
}

// ---------------------------------------------------------------------------
// K1 (MFMA): h1 = x @ W1. Per wave: 64 rows x 64 cols via 4x4 tiles of
// mfma_f32_16x16x32_bf16. W1 bf16-swizzled in LDS (B-frag = 1 ds_read_b128);
// x loaded fp32 + packed cvt in-register. Epilogue stages h in LDS (padded)
// for per-node s1/d1 dots + vectorized bf16 h1b stores.
// ---------------------------------------------------------------------------
__global__ __launch_bounds__(256) void k_gemm1(
        const float* __restrict__ x, const float* __restrict__ W1,
        const float* __restrict__ as1, const float* __restrict__ ad1,
        ushort* __restrict__ h1b, float* __restrict__ s1, float* __restrict__ d1) {
    __shared__ union {
        ushort B[F_IN * F1];        // 32 KB: W1 bf16, idx = ((k>>3)*64+n)*8 + (k&7)
        ushort S[4][64][66];        // 33.8 KB: per-wave h staging (pad 66)
    } sm;
    const int tid = threadIdx.x;

    for (int i = 0; i < 64; ++i) {                 // stage + swizzle W1
        const int e = i * 256 + tid;               // e = k*64 + n
        const int k = e >> 6, n = e & 63;
        sm.B[((k >> 3) * 64 + n) * 8 + (k & 7)] = f2bf(W1[e]);
    }
    __syncthreads();

    const int wave = tid >> 6, lane = tid & 63;
    const int q = lane >> 4, ln = lane & 15;
    const int rowbase = blockIdx.x * 256 + wave * 64;

    f32x4 acc[4][4];
#pragma unroll
    for (int mt = 0; mt < 4; ++mt)
#pragma unroll
        for (int nt = 0; nt < 4; ++nt) acc[mt][nt] = (f32x4){0.f, 0.f, 0.f, 0.f};

    int rows[4];
#pragma unroll
    for (int mt = 0; mt < 4; ++mt) {
        const int r = rowbase + mt * 16 + ln;      // A: m = lane&15
        rows[mt] = r < N_NODES ? r : N_NODES - 1;  // clamp (dup loads harmless)
    }

    for (int t = 0; t < 8; ++t) {                  // K-loop: 8 x 32
        bf16x8 bfr[4];
#pragma unroll
        for (int nt = 0; nt < 4; ++nt)             // B-frag: n=lane&15, k=q*8+j
            bfr[nt] = *(const bf16x8*)&sm.B[((t * 4 + q) * 64 + nt * 16 + ln) * 8];
#pragma unroll
        for (int mt = 0; mt < 4; ++mt) {
            const float4* ap = (const float4*)(x + (size_t)rows[mt] * F_IN + t * 32 + q * 8);
            const float4 a0 = ap[0], a1 = ap[1];
            uint4 au = make_uint4(pk2bf(a0.x, a0.y), pk2bf(a0.z, a0.w),
                                  pk2bf(a1.x, a1.y), pk2bf(a1.z, a1.w));
            bf16x8 af = *(bf16x8*)&au;
#pragma unroll
            for (int nt = 0; nt < 4; ++nt)
                acc[mt][nt] = __builtin_amdgcn_mfma_f32_16x16x32_bf16(
                                  af, bfr[nt], acc[mt][nt], 0, 0, 0);
        }
    }
    __syncthreads();                               // all waves done with sm.B

    // stage h (bf16): C/D layout col=lane&15, row=q*4+r  [m89/m91]
#pragma unroll
    for (int mt = 0; mt < 4; ++mt)
#pragma unroll
        for (int nt = 0; nt < 4; ++nt)
#pragma unroll
            for (int r = 0; r < 4; ++r)
                sm.S[wave][mt * 16 + q * 4 + r][nt * 16 + ln] = f2bf(acc[mt][nt][r]);
    __syncthreads();

    // per-node epilogue: lane = node_local
    const int node = rowbase + lane;
    if (node >= N_NODES) return;
    const uint* srow = (const uint*)&sm.S[wave][lane][0];   // 32 bf16 pairs
    float sacc[H1], dacc[H1];
#pragma unroll
    for (int h = 0; h < H1; ++h) { sacc[h] = 0.f; dacc[h] = 0.f; }
    uint4* hout = (uint4*)(h1b + (size_t)node * F1);
#pragma unroll
    for (int p4 = 0; p4 < 8; ++p4) {               // p4 == head index
        const uint u0 = srow[p4 * 4 + 0], u1 = srow[p4 * 4 + 1];
        const uint u2 = srow[p4 * 4 + 2], u3 = srow[p4 * 4 + 3];
        hout[p4] = make_uint4(u0, u1, u2, u3);
        const float c[8] = {bflo(u0), bfhi(u0), bflo(u1), bfhi(u1),
                            bflo(u2), bfhi(u2), bflo(u3), bfhi(u3)};
#pragma unroll
        for (int j = 0; j < 8; ++j) {
            sacc[p4] += c[j] * as1[p4 * 8 + j];    // uniform -> scalar loads
            dacc[p4] += c[j] * ad1[p4 * 8 + j];
        }
    }
    float4* s4 = (float4*)(s1 + (size_t)node * H1);
    float4* d4 = (float4*)(d1 + (size_t)node * H1);
    s4[0] = make_float4(sacc[0], sacc[1], sacc[2], sacc[3]);
    s4[1] = make_float4(sacc[4], sacc[5], sacc[6], sacc[7]);
    d4[0] = make_float4(dacc[0], dacc[1], dacc[2], dacc[3]);
    d4[1] = make_float4(dacc[4], dacc[5], dacc[6], dacc[7]);
}

// ---------------------------------------------------------------------------
// CSR build: histogram -> hierarchical exclusive scan -> scatter.
// ---------------------------------------------------------------------------
__global__ __launch_bounds__(256) void k_hist(
        const int* __restrict__ ei, int* __restrict__ cnt) {
    const int e = blockIdx.x * 256 + threadIdx.x;
    if (e >= N_TOT) return;
    const int di = (e < N_EDGES) ? ei[N_EDGES + e] : (e - N_EDGES);
    atomicAdd(cnt + di, 1);
}

__global__ __launch_bounds__(256) void k_scan_a(
        const int* __restrict__ cnt, int* __restrict__ row_ptr,
        int* __restrict__ bsum) {
    __shared__ int sdata[256];
    const int tid = threadIdx.x;
    const int base = blockIdx.x * CHUNK + tid * 8;
    int v[8];
    int tot = 0;
#pragma unroll
    for (int j = 0; j < 8; ++j) {
        v[j] = (base + j < N_NODES) ? cnt[base + j] : 0;
        tot += v[j];
    }
    sdata[tid] = tot;
    __syncthreads();
    for (int off = 1; off < 256; off <<= 1) {
        int t = (tid >= off) ? sdata[tid - off] : 0;
        __syncthreads();
        sdata[tid] += t;
        __syncthreads();
    }
    int run = sdata[tid] - tot;
#pragma unroll
    for (int j = 0; j < 8; ++j) {
        if (base + j < N_NODES) row_ptr[base + j] = run;
        run += v[j];
    }
    if (tid == 255) bsum[blockIdx.x] = sdata[255];
}

__global__ __launch_bounds__(64) void k_scan_b(int* __restrict__ bsum) {
    const int t = threadIdx.x;
    int v = (t < NCH) ? bsum[t] : 0;
    const int orig = v;
    for (int off = 1; off < 64; off <<= 1) {
        int u = __shfl_up(v, off);
        if (t >= off) v += u;
    }
    if (t < NCH) bsum[t] = v - orig;
}

__global__ __launch_bounds__(256) void k_scan_c(
        int* __restrict__ row_ptr, const int* __restrict__ bsum) {
    const int i = blockIdx.x * 256 + threadIdx.x;
    if (i < N_NODES) row_ptr[i] += bsum[i / CHUNK];
    else if (i == N_NODES) row_ptr[N_NODES] = N_TOT;
}

__global__ __launch_bounds__(256) void k_scatter(
        const int* __restrict__ ei, const int* __restrict__ row_ptr,
        int* __restrict__ tmp, int* __restrict__ srcs) {
    const int e = blockIdx.x * 256 + threadIdx.x;
    if (e >= N_TOT) return;
    int si, di;
    if (e < N_EDGES) { si = ei[e]; di = ei[N_EDGES + e]; }
    else             { si = di = e - N_EDGES; }
    const int pos = row_ptr[di] + atomicAdd(tmp + di, 1);
    srcs[pos] = si;
}

// ---------------------------------------------------------------------------
// K_agg1: half-wave per edge (2 edges/wave-iter), unroll x2 (4 gathers in
// flight). Lane holds a bf16 channel pair. Emits x2 = elu(agg/z + b1) bf16.
// ---------------------------------------------------------------------------
__global__ __launch_bounds__(256) void k_agg1(
        const int* __restrict__ row_ptr, const int* __restrict__ srcs,
        const ushort* __restrict__ h1b, const float* __restrict__ s1,
        const float* __restrict__ d1, const float* __restrict__ b1,
        ushort* __restrict__ x2b) {
    const int wid = (blockIdx.x * 256 + threadIdx.x) >> 6;
    if (wid >= N_NODES) return;
    const int lane = threadIdx.x & 63;
    const int half = lane >> 5;
    const int c = lane & 31;          // channel pair index: channels 2c, 2c+1
    const int hd = c >> 2;            // head
    const float dh = d1[(size_t)wid * H1 + hd];
    const int beg = row_ptr[wid], end = row_ptr[wid + 1];
    const uint* hv = (const uint*)h1b;    // 32 uints per node
    float ax = 0.f, ay = 0.f, z = 0.f;
    int i = beg + half;
    for (; i + 2 < end; i += 4) {
        const int sA = srcs[i], sB = srcs[i + 2];
        float eA = s1[(size_t)sA * H1 + hd] + dh;
        float eB = s1[(size_t)sB * H1 + hd] + dh;
        eA = eA > 0.f ? eA : SLOPE * eA;
        eB = eB > 0.f ? eB : SLOPE * eB;
        const float xA = __expf(eA), xB = __expf(eB);
        const uint uA = hv[(size_t)sA * 32 + c];
        const uint uB = hv[(size_t)sB * 32 + c];
        z  += xA + xB;
        ax += xA * bflo(uA) + xB * bflo(uB);
        ay += xA * bfhi(uA) + xB * bfhi(uB);
    }
    for (; i < end; i += 2) {
        const int sA = srcs[i];
        float eA = s1[(size_t)sA * H1 + hd] + dh;
        eA = eA > 0.f ? eA : SLOPE * eA;
        const float xA = __expf(eA);
        const uint uA = hv[(size_t)sA * 32 + c];
        z  += xA;
        ax += xA * bflo(uA);
        ay += xA * bfhi(uA);
    }
    ax += __shfl_xor(ax, 32);
    ay += __shfl_xor(ay, 32);
    z  += __shfl_xor(z, 32);
    if (half == 0) {
        const float zi = 1.f / (z + 1e-16f);
        float v0 = ax * zi + b1[2 * c];
        float v1 = ay * zi + b1[2 * c + 1];
        v0 = v0 > 0.f ? v0 : __expf(v0) - 1.f;
        v1 = v1 > 0.f ? v1 : __expf(v1) - 1.f;
        ((uint*)x2b)[(size_t)wid * 32 + c] = (uint)f2bf(v0) | ((uint)f2bf(v1) << 16);
    }
}

// ---------------------------------------------------------------------------
// K_node1: h2 = x2 @ W2 (x2 bf16 in, h2 bf16 out, W2 in LDS), fused s2/d2.
// ---------------------------------------------------------------------------
__global__ __launch_bounds__(256) void k_node1(
        const ushort* __restrict__ x2b, const float* __restrict__ W2,
        const float* __restrict__ as2, const float* __restrict__ ad2,
        ushort* __restrict__ h2b, float* __restrict__ s2, float* __restrict__ d2) {
    __shared__ float sW[F1 * F2];           // 8 KB
    const int tid = threadIdx.x;
    const float4* W4 = (const float4*)W2;
    float4* sW4 = (float4*)sW;
#pragma unroll
    for (int i = 0; i < (F1 * F2 / 4) / 256; ++i)
        sW4[i * 256 + tid] = W4[i * 256 + tid];
    __syncthreads();

    const int n = blockIdx.x * 256 + tid;
    if (n >= N_NODES) return;

    float acc[F2];
#pragma unroll
    for (int c = 0; c < F2; ++c) acc[c] = 0.f;

    const uint4* xv4 = (const uint4*)(x2b + (size_t)n * F1);   // 8 loads
#pragma unroll
    for (int q = 0; q < 8; ++q) {
        uint4 u = xv4[q];
        float xs[8] = {bflo(u.x), bfhi(u.x), bflo(u.y), bfhi(u.y),
                       bflo(u.z), bfhi(u.z), bflo(u.w), bfhi(u.w)};
#pragma unroll
        for (int kk = 0; kk < 8; ++kk) {
            const float t = xs[kk];
            const float4* wr = (const float4*)(sW + (q * 8 + kk) * F2);
#pragma unroll
            for (int c4 = 0; c4 < F2 / 4; ++c4) {
                float4 w = wr[c4];
                acc[c4 * 4 + 0] += t * w.x;
                acc[c4 * 4 + 1] += t * w.y;
                acc[c4 * 4 + 2] += t * w.z;
                acc[c4 * 4 + 3] += t * w.w;
            }
        }
    }

    uint up[F2 / 2];
#pragma unroll
    for (int j = 0; j < F2 / 2; ++j)
        up[j] = (uint)f2bf(acc[2 * j]) | ((uint)f2bf(acc[2 * j + 1]) << 16);
    uint4* o4 = (uint4*)(h2b + (size_t)n * F2);
#pragma unroll
    for (int q = 0; q < F2 / 8; ++q)
        o4[q] = make_uint4(up[q * 4 + 0], up[q * 4 + 1], up[q * 4 + 2], up[q * 4 + 3]);

    float s = 0.f, d = 0.f;
#pragma unroll
    for (int c = 0; c < F2; ++c) { s += acc[c] * as2[c]; d += acc[c] * ad2[c]; }
    s2[n] = s;
    d2[n] = d;
}

// ---------------------------------------------------------------------------
// K_agg2: quarter-wave per edge (4 edges/wave-iter), unroll x2 (8 gathers in
// flight). Fused log_softmax (16-lane shfl). Writes d_out directly.
// ---------------------------------------------------------------------------
__global__ __launch_bounds__(256) void k_agg2(
        const int* __restrict__ row_ptr, const int* __restrict__ srcs,
        const ushort* __restrict__ h2b, const float* __restrict__ s2,
        const float* __restrict__ d2, const float* __restrict__ b2,
        float* __restrict__ out) {
    const int wid = (blockIdx.x * 256 + threadIdx.x) >> 6;
    if (wid >= N_NODES) return;
    const int lane = threadIdx.x & 63;
    const int q = lane >> 4;
    const int c = lane & 15;          // channel pair index: channels 2c, 2c+1
    const float dn = d2[wid];
    const int beg = row_ptr[wid], end = row_ptr[wid + 1];
    const uint* hv = (const uint*)h2b;    // 16 uints per node
    float ax = 0.f, ay = 0.f, z = 0.f;
    int i = beg + q;
    for (; i + 4 < end; i += 8) {
        const int sA = srcs[i], sB = srcs[i + 4];
        float eA = s2[sA] + dn;
        float eB = s2[sB] + dn;
        eA = eA > 0.f ? eA : SLOPE * eA;
        eB = eB > 0.f ? eB : SLOPE * eB;
        const float xA = __expf(eA), xB = __expf(eB);
        const uint uA = hv[(size_t)sA * 16 + c];
        const uint uB = hv[(size_t)sB * 16 + c];
        z  += xA + xB;
        ax += xA * bflo(uA) + xB * bflo(uB);
        ay += xA * bfhi(uA) + xB * bfhi(uB);
    }
    for (; i < end; i += 4) {
        const int sA = srcs[i];
        float eA = s2[sA] + dn;
        eA = eA > 0.f ? eA : SLOPE * eA;
        const float xA = __expf(eA);
        const uint uA = hv[(size_t)sA * 16 + c];
        z  += xA;
        ax += xA * bflo(uA);
        ay += xA * bfhi(uA);
    }
    ax += __shfl_xor(ax, 16); ax += __shfl_xor(ax, 32);
    ay += __shfl_xor(ay, 16); ay += __shfl_xor(ay, 32);
    z  += __shfl_xor(z, 16);  z  += __shfl_xor(z, 32);

    const float zi = 1.f / (z + 1e-16f);
    const float v0 = ax * zi + b2[2 * c];
    const float v1 = ay * zi + b2[2 * c + 1];
    float m = fmaxf(v0, v1);
#pragma unroll
    for (int off = 8; off >= 1; off >>= 1) m = fmaxf(m, __shfl_xor(m, off));
    float ssum = __expf(v0 - m) + __expf(v1 - m);
#pragma unroll
    for (int off = 8; off >= 1; off >>= 1) ssum += __shfl_xor(ssum, off);
    const float lse = m + __logf(ssum);
    if (lane < 16)
        ((float2*)out)[(size_t)wid * 16 + c] = make_float2(v0 - lse, v1 - lse);
}

extern "C" void kernel_launch(void* const* d_in, const int* in_sizes, int n_in,
                              void* d_out, int out_size, void* d_ws, size_t ws_size,
                              hipStream_t stream) {
    const float* x   = (const float*)d_in[0];
    const int*   ei  = (const int*)d_in[1];
    const float* W1  = (const float*)d_in[2];
    const float* as1 = (const float*)d_in[3];
    const float* ad1 = (const float*)d_in[4];
    const float* b1  = (const float*)d_in[5];
    const float* W2  = (const float*)d_in[6];
    const float* as2 = (const float*)d_in[7];
    const float* ad2 = (const float*)d_in[8];
    const float* b2  = (const float*)d_in[9];
    float* out = (float*)d_out;

    // Workspace: bf16 tables first (16B-aligned rows), then fp32, then ints.
    ushort* h1b = (ushort*)d_ws;                   // N*64 bf16
    ushort* x2b = h1b + (size_t)N_NODES * F1;      // N*64 bf16
    ushort* h2b = x2b + (size_t)N_NODES * F1;      // N*32 bf16
    float*  s1  = (float*)(h2b + (size_t)N_NODES * F2);  // N*8
    float*  d1  = s1 + (size_t)N_NODES * H1;       // N*8
    float*  s2  = d1 + (size_t)N_NODES * H1;       // N
    float*  d2  = s2 + N_NODES;                    // N
    int* cnt     = (int*)(d2 + N_NODES);           // N
    int* tmp     = cnt + N_NODES;                  // N
    int* row_ptr = tmp + N_NODES;                  // N+1
    int* bsum    = row_ptr + N_NODES + 1;          // 64
    int* srcs    = bsum + 64;                      // N_TOT

    hipMemsetAsync(cnt, 0, (size_t)N_NODES * sizeof(int), stream);
    hipMemsetAsync(tmp, 0, (size_t)N_NODES * sizeof(int), stream);

    const int nb_n = (N_NODES + 255) / 256;
    const int nb_e = (N_TOT + 255) / 256;
    const int nb_w = (N_NODES * 64 + 255) / 256;   // one wave per node

    k_gemm1<<<nb_n, 256, 0, stream>>>(x, W1, as1, ad1, h1b, s1, d1);
    k_hist<<<nb_e, 256, 0, stream>>>(ei, cnt);
    k_scan_a<<<NCH, 256, 0, stream>>>(cnt, row_ptr, bsum);
    k_scan_b<<<1, 64, 0, stream>>>(bsum);
    k_scan_c<<<(N_NODES + 256) / 256, 256, 0, stream>>>(row_ptr, bsum);
    k_scatter<<<nb_e, 256, 0, stream>>>(ei, row_ptr, tmp, srcs);
    k_agg1<<<nb_w, 256, 0, stream>>>(row_ptr, srcs, h1b, s1, d1, b1, x2b);
    k_node1<<<nb_n, 256, 0, stream>>>(x2b, W2, as2, ad2, h2b, s2, d2);
    k_agg2<<<nb_w, 256, 0, stream>>>(row_ptr, srcs, h2b, s2, d2, b2, out);
}

// Round 5
// 424.614 us; speedup vs baseline: 22.1680x; 1.1323x over previous
//
#include <hip/hip_runtime.h>
#include <hip/hip_bf16.h>

#define N_NODES 100000
#define N_EDGES 1600000
#define N_TOT   (N_EDGES + N_NODES)   // edges + self loops
#define F_IN    256
#define F1      64     // H1*C1
#define H1      8
#define C1      8
#define F2      32
#define SLOPE   0.2f
#define CHUNK   2048
#define NCH     ((N_NODES + CHUNK - 1) / CHUNK)   // 49

#define NB_G    ((N_NODES + 255) / 256)           // 391 gemm blocks
#define NB_H    ((N_TOT + 255) / 256)             // 6641 hist blocks

#define SLICES  8                                  // one dst-slice per XCD
#define SL_W    ((N_NODES + SLICES - 1) / SLICES)  // 12500 nodes/slice
#define CH_E    16384                              // edges per scatter chunk
#define NCHUNK  ((N_TOT + CH_E - 1) / CH_E)        // 104

typedef unsigned int  uint;
typedef unsigned short ushort;
typedef __attribute__((ext_vector_type(8))) short bf16x8;
typedef __attribute__((ext_vector_type(4))) float f32x4;

__device__ inline ushort f2bf(float f) {               // RNE float->bf16
    uint u = __float_as_uint(f);
    uint r = u + 0x7fffu + ((u >> 16) & 1u);
    return (ushort)(r >> 16);
}
__device__ inline float bflo(uint u) { return __uint_as_float(u << 16); }
__device__ inline float bfhi(uint u) { return __uint_as_float(u & 0xffff0000u); }
__device__ inline uint pk2bf(float a, float b) {
    __hip_bfloat162 h = __float22bfloat162_rn(make_float2(a, b));
    union { __hip_bfloat162 h; uint u; } cv; cv.h = h;
    return cv.u;
}

// ---------------------------------------------------------------------------
// K1 fused: blocks [0,NB_G) run the MFMA gemm (h1 = x@W1 + s1/d1 dots);
// blocks [NB_G, NB_G+NB_H) run hist+rank (rank[e] = atomicAdd(cnt[dst],1)).
// Independent work; hist hides under the gemm window on idle CUs.
// ---------------------------------------------------------------------------
__global__ __launch_bounds__(256) void k_gemm1_hist(
        const float* __restrict__ x, const float* __restrict__ W1,
        const float* __restrict__ as1, const float* __restrict__ ad1,
        const int* __restrict__ ei,
        ushort* __restrict__ h1b, float* __restrict__ s1, float* __restrict__ d1,
        int* __restrict__ cnt, int* __restrict__ rank) {
    __shared__ union {
        ushort B[F_IN * F1];        // 32 KB: W1 bf16, idx = ((k>>3)*64+n)*8 + (k&7)
        ushort S[4][64][66];        // 33.8 KB: per-wave h staging (pad 66)
    } sm;
    const int tid = threadIdx.x;

    if (blockIdx.x >= NB_G) {                      // ---- hist + rank part ----
        const int e = (blockIdx.x - NB_G) * 256 + tid;
        if (e < N_TOT) {
            const int di = (e < N_EDGES) ? ei[N_EDGES + e] : (e - N_EDGES);
            rank[e] = atomicAdd(cnt + di, 1);
        }
        return;
    }

    // ---- MFMA gemm part ----
    for (int i = 0; i < 64; ++i) {                 // stage + swizzle W1
        const int e = i * 256 + tid;               // e = k*64 + n
        const int k = e >> 6, n = e & 63;
        sm.B[((k >> 3) * 64 + n) * 8 + (k & 7)] = f2bf(W1[e]);
    }
    __syncthreads();

    const int wave = tid >> 6, lane = tid & 63;
    const int q = lane >> 4, ln = lane & 15;
    const int rowbase = blockIdx.x * 256 + wave * 64;

    f32x4 acc[4][4];
#pragma unroll
    for (int mt = 0; mt < 4; ++mt)
#pragma unroll
        for (int nt = 0; nt < 4; ++nt) acc[mt][nt] = (f32x4){0.f, 0.f, 0.f, 0.f};

    int rows[4];
#pragma unroll
    for (int mt = 0; mt < 4; ++mt) {
        const int r = rowbase + mt * 16 + ln;
        rows[mt] = r < N_NODES ? r : N_NODES - 1;
    }

    for (int t = 0; t < 8; ++t) {                  // K-loop: 8 x 32
        bf16x8 bfr[4];
#pragma unroll
        for (int nt = 0; nt < 4; ++nt)
            bfr[nt] = *(const bf16x8*)&sm.B[((t * 4 + q) * 64 + nt * 16 + ln) * 8];
#pragma unroll
        for (int mt = 0; mt < 4; ++mt) {
            const float4* ap = (const float4*)(x + (size_t)rows[mt] * F_IN + t * 32 + q * 8);
            const float4 a0 = ap[0], a1 = ap[1];
            uint4 au = make_uint4(pk2bf(a0.x, a0.y), pk2bf(a0.z, a0.w),
                                  pk2bf(a1.x, a1.y), pk2bf(a1.z, a1.w));
            bf16x8 af = *(bf16x8*)&au;
#pragma unroll
            for (int nt = 0; nt < 4; ++nt)
                acc[mt][nt] = __builtin_amdgcn_mfma_f32_16x16x32_bf16(
                                  af, bfr[nt], acc[mt][nt], 0, 0, 0);
        }
    }
    __syncthreads();

    // stage h (bf16): C/D layout col=lane&15, row=q*4+r
#pragma unroll
    for (int mt = 0; mt < 4; ++mt)
#pragma unroll
        for (int nt = 0; nt < 4; ++nt)
#pragma unroll
            for (int r = 0; r < 4; ++r)
                sm.S[wave][mt * 16 + q * 4 + r][nt * 16 + ln] = f2bf(acc[mt][nt][r]);
    __syncthreads();

    const int node = rowbase + lane;
    if (node >= N_NODES) return;
    const uint* srow = (const uint*)&sm.S[wave][lane][0];
    float sacc[H1], dacc[H1];
#pragma unroll
    for (int h = 0; h < H1; ++h) { sacc[h] = 0.f; dacc[h] = 0.f; }
    uint4* hout = (uint4*)(h1b + (size_t)node * F1);
#pragma unroll
    for (int p4 = 0; p4 < 8; ++p4) {               // p4 == head index
        const uint u0 = srow[p4 * 4 + 0], u1 = srow[p4 * 4 + 1];
        const uint u2 = srow[p4 * 4 + 2], u3 = srow[p4 * 4 + 3];
        hout[p4] = make_uint4(u0, u1, u2, u3);
        const float c[8] = {bflo(u0), bfhi(u0), bflo(u1), bfhi(u1),
                            bflo(u2), bfhi(u2), bflo(u3), bfhi(u3)};
#pragma unroll
        for (int j = 0; j < 8; ++j) {
            sacc[p4] += c[j] * as1[p4 * 8 + j];
            dacc[p4] += c[j] * ad1[p4 * 8 + j];
        }
    }
    float4* s4 = (float4*)(s1 + (size_t)node * H1);
    float4* d4 = (float4*)(d1 + (size_t)node * H1);
    s4[0] = make_float4(sacc[0], sacc[1], sacc[2], sacc[3]);
    s4[1] = make_float4(sacc[4], sacc[5], sacc[6], sacc[7]);
    d4[0] = make_float4(dacc[0], dacc[1], dacc[2], dacc[3]);
    d4[1] = make_float4(dacc[4], dacc[5], dacc[6], dacc[7]);
}

// ---------------------------------------------------------------------------
// Scan over cnt -> row_ptr (hierarchical, 3 small kernels).
// ---------------------------------------------------------------------------
__global__ __launch_bounds__(256) void k_scan_a(
        const int* __restrict__ cnt, int* __restrict__ row_ptr,
        int* __restrict__ bsum) {
    __shared__ int sdata[256];
    const int tid = threadIdx.x;
    const int base = blockIdx.x * CHUNK + tid * 8;
    int v[8];
    int tot = 0;
#pragma unroll
    for (int j = 0; j < 8; ++j) {
        v[j] = (base + j < N_NODES) ? cnt[base + j] : 0;
        tot += v[j];
    }
    sdata[tid] = tot;
    __syncthreads();
    for (int off = 1; off < 256; off <<= 1) {
        int t = (tid >= off) ? sdata[tid - off] : 0;
        __syncthreads();
        sdata[tid] += t;
        __syncthreads();
    }
    int run = sdata[tid] - tot;
#pragma unroll
    for (int j = 0; j < 8; ++j) {
        if (base + j < N_NODES) row_ptr[base + j] = run;
        run += v[j];
    }
    if (tid == 255) bsum[blockIdx.x] = sdata[255];
}

__global__ __launch_bounds__(64) void k_scan_b(int* __restrict__ bsum) {
    const int t = threadIdx.x;
    int v = (t < NCH) ? bsum[t] : 0;
    const int orig = v;
    for (int off = 1; off < 64; off <<= 1) {
        int u = __shfl_up(v, off);
        if (t >= off) v += u;
    }
    if (t < NCH) bsum[t] = v - orig;
}

__global__ __launch_bounds__(256) void k_scan_c(
        int* __restrict__ row_ptr, const int* __restrict__ bsum) {
    const int i = blockIdx.x * 256 + threadIdx.x;
    if (i < N_NODES) row_ptr[i] += bsum[i / CHUNK];
    else if (i == N_NODES) row_ptr[N_NODES] = N_TOT;
}

// ---------------------------------------------------------------------------
// Sliced atomic-free scatter: slice = blockIdx%8 -> pinned to one XCD
// (round-robin dispatch). Each XCD writes only its ~850 KB srcs slice ->
// L2-resident, no write amplification. Edge list re-read 8x from L3.
// ---------------------------------------------------------------------------
__global__ __launch_bounds__(256) void k_scatter(
        const int* __restrict__ ei, const int* __restrict__ row_ptr,
        const int* __restrict__ rank, int* __restrict__ srcs) {
    const int slice = blockIdx.x % SLICES;
    const int chunk = blockIdx.x / SLICES;
    const int lo = slice * SL_W;
    const int base = chunk * CH_E;
    const int lim = (base + CH_E < N_TOT) ? base + CH_E : N_TOT;
    for (int i = base + threadIdx.x; i < lim; i += 256) {
        const int di = (i < N_EDGES) ? ei[N_EDGES + i] : (i - N_EDGES);
        if ((uint)(di - lo) < (uint)SL_W) {
            const int si = (i < N_EDGES) ? ei[i] : di;
            srcs[row_ptr[di] + rank[i]] = si;
        }
    }
}

// ---------------------------------------------------------------------------
// K_agg1: half-wave per edge (2 edges/wave-iter), unroll x2 (4 gathers in
// flight). Lane holds a bf16 channel pair. Emits x2 = elu(agg/z + b1) bf16.
// ---------------------------------------------------------------------------
__global__ __launch_bounds__(256) void k_agg1(
        const int* __restrict__ row_ptr, const int* __restrict__ srcs,
        const ushort* __restrict__ h1b, const float* __restrict__ s1,
        const float* __restrict__ d1, const float* __restrict__ b1,
        ushort* __restrict__ x2b) {
    const int wid = (blockIdx.x * 256 + threadIdx.x) >> 6;
    if (wid >= N_NODES) return;
    const int lane = threadIdx.x & 63;
    const int half = lane >> 5;
    const int c = lane & 31;          // channel pair index: channels 2c, 2c+1
    const int hd = c >> 2;            // head
    const float dh = d1[(size_t)wid * H1 + hd];
    const int beg = row_ptr[wid], end = row_ptr[wid + 1];
    const uint* hv = (const uint*)h1b;    // 32 uints per node
    float ax = 0.f, ay = 0.f, z = 0.f;
    int i = beg + half;
    for (; i + 2 < end; i += 4) {
        const int sA = srcs[i], sB = srcs[i + 2];
        float eA = s1[(size_t)sA * H1 + hd] + dh;
        float eB = s1[(size_t)sB * H1 + hd] + dh;
        eA = eA > 0.f ? eA : SLOPE * eA;
        eB = eB > 0.f ? eB : SLOPE * eB;
        const float xA = __expf(eA), xB = __expf(eB);
        const uint uA = hv[(size_t)sA * 32 + c];
        const uint uB = hv[(size_t)sB * 32 + c];
        z  += xA + xB;
        ax += xA * bflo(uA) + xB * bflo(uB);
        ay += xA * bfhi(uA) + xB * bfhi(uB);
    }
    for (; i < end; i += 2) {
        const int sA = srcs[i];
        float eA = s1[(size_t)sA * H1 + hd] + dh;
        eA = eA > 0.f ? eA : SLOPE * eA;
        const float xA = __expf(eA);
        const uint uA = hv[(size_t)sA * 32 + c];
        z  += xA;
        ax += xA * bflo(uA);
        ay += xA * bfhi(uA);
    }
    ax += __shfl_xor(ax, 32);
    ay += __shfl_xor(ay, 32);
    z  += __shfl_xor(z, 32);
    if (half == 0) {
        const float zi = 1.f / (z + 1e-16f);
        float v0 = ax * zi + b1[2 * c];
        float v1 = ay * zi + b1[2 * c + 1];
        v0 = v0 > 0.f ? v0 : __expf(v0) - 1.f;
        v1 = v1 > 0.f ? v1 : __expf(v1) - 1.f;
        ((uint*)x2b)[(size_t)wid * 32 + c] = (uint)f2bf(v0) | ((uint)f2bf(v1) << 16);
    }
}

// ---------------------------------------------------------------------------
// K_node1: h2 = x2 @ W2 (x2 bf16 in, h2 bf16 out, W2 in LDS), fused s2/d2.
// ---------------------------------------------------------------------------
__global__ __launch_bounds__(256) void k_node1(
        const ushort* __restrict__ x2b, const float* __restrict__ W2,
        const float* __restrict__ as2, const float* __restrict__ ad2,
        ushort* __restrict__ h2b, float* __restrict__ s2, float* __restrict__ d2) {
    __shared__ float sW[F1 * F2];           // 8 KB
    const int tid = threadIdx.x;
    const float4* W4 = (const float4*)W2;
    float4* sW4 = (float4*)sW;
#pragma unroll
    for (int i = 0; i < (F1 * F2 / 4) / 256; ++i)
        sW4[i * 256 + tid] = W4[i * 256 + tid];
    __syncthreads();

    const int n = blockIdx.x * 256 + tid;
    if (n >= N_NODES) return;

    float acc[F2];
#pragma unroll
    for (int c = 0; c < F2; ++c) acc[c] = 0.f;

    const uint4* xv4 = (const uint4*)(x2b + (size_t)n * F1);   // 8 loads
#pragma unroll
    for (int q = 0; q < 8; ++q) {
        uint4 u = xv4[q];
        float xs[8] = {bflo(u.x), bfhi(u.x), bflo(u.y), bfhi(u.y),
                       bflo(u.z), bfhi(u.z), bflo(u.w), bfhi(u.w)};
#pragma unroll
        for (int kk = 0; kk < 8; ++kk) {
            const float t = xs[kk];
            const float4* wr = (const float4*)(sW + (q * 8 + kk) * F2);
#pragma unroll
            for (int c4 = 0; c4 < F2 / 4; ++c4) {
                float4 w = wr[c4];
                acc[c4 * 4 + 0] += t * w.x;
                acc[c4 * 4 + 1] += t * w.y;
                acc[c4 * 4 + 2] += t * w.z;
                acc[c4 * 4 + 3] += t * w.w;
            }
        }
    }

    uint up[F2 / 2];
#pragma unroll
    for (int j = 0; j < F2 / 2; ++j)
        up[j] = (uint)f2bf(acc[2 * j]) | ((uint)f2bf(acc[2 * j + 1]) << 16);
    uint4* o4 = (uint4*)(h2b + (size_t)n * F2);
#pragma unroll
    for (int q = 0; q < F2 / 8; ++q)
        o4[q] = make_uint4(up[q * 4 + 0], up[q * 4 + 1], up[q * 4 + 2], up[q * 4 + 3]);

    float s = 0.f, d = 0.f;
#pragma unroll
    for (int c = 0; c < F2; ++c) { s += acc[c] * as2[c]; d += acc[c] * ad2[c]; }
    s2[n] = s;
    d2[n] = d;
}

// ---------------------------------------------------------------------------
// K_agg2: quarter-wave per edge (4 edges/wave-iter), unroll x2 (8 gathers in
// flight). Fused log_softmax (16-lane shfl). Writes d_out directly.
// ---------------------------------------------------------------------------
__global__ __launch_bounds__(256) void k_agg2(
        const int* __restrict__ row_ptr, const int* __restrict__ srcs,
        const ushort* __restrict__ h2b, const float* __restrict__ s2,
        const float* __restrict__ d2, const float* __restrict__ b2,
        float* __restrict__ out) {
    const int wid = (blockIdx.x * 256 + threadIdx.x) >> 6;
    if (wid >= N_NODES) return;
    const int lane = threadIdx.x & 63;
    const int q = lane >> 4;
    const int c = lane & 15;          // channel pair index: channels 2c, 2c+1
    const float dn = d2[wid];
    const int beg = row_ptr[wid], end = row_ptr[wid + 1];
    const uint* hv = (const uint*)h2b;    // 16 uints per node
    float ax = 0.f, ay = 0.f, z = 0.f;
    int i = beg + q;
    for (; i + 4 < end; i += 8) {
        const int sA = srcs[i], sB = srcs[i + 4];
        float eA = s2[sA] + dn;
        float eB = s2[sB] + dn;
        eA = eA > 0.f ? eA : SLOPE * eA;
        eB = eB > 0.f ? eB : SLOPE * eB;
        const float xA = __expf(eA), xB = __expf(eB);
        const uint uA = hv[(size_t)sA * 16 + c];
        const uint uB = hv[(size_t)sB * 16 + c];
        z  += xA + xB;
        ax += xA * bflo(uA) + xB * bflo(uB);
        ay += xA * bfhi(uA) + xB * bfhi(uB);
    }
    for (; i < end; i += 4) {
        const int sA = srcs[i];
        float eA = s2[sA] + dn;
        eA = eA > 0.f ? eA : SLOPE * eA;
        const float xA = __expf(eA);
        const uint uA = hv[(size_t)sA * 16 + c];
        z  += xA;
        ax += xA * bflo(uA);
        ay += xA * bfhi(uA);
    }
    ax += __shfl_xor(ax, 16); ax += __shfl_xor(ax, 32);
    ay += __shfl_xor(ay, 16); ay += __shfl_xor(ay, 32);
    z  += __shfl_xor(z, 16);  z  += __shfl_xor(z, 32);

    const float zi = 1.f / (z + 1e-16f);
    const float v0 = ax * zi + b2[2 * c];
    const float v1 = ay * zi + b2[2 * c + 1];
    float m = fmaxf(v0, v1);
#pragma unroll
    for (int off = 8; off >= 1; off >>= 1) m = fmaxf(m, __shfl_xor(m, off));
    float ssum = __expf(v0 - m) + __expf(v1 - m);
#pragma unroll
    for (int off = 8; off >= 1; off >>= 1) ssum += __shfl_xor(ssum, off);
    const float lse = m + __logf(ssum);
    if (lane < 16)
        ((float2*)out)[(size_t)wid * 16 + c] = make_float2(v0 - lse, v1 - lse);
}

extern "C" void kernel_launch(void* const* d_in, const int* in_sizes, int n_in,
                              void* d_out, int out_size, void* d_ws, size_t ws_size,
                              hipStream_t stream) {
    const float* x   = (const float*)d_in[0];
    const int*   ei  = (const int*)d_in[1];
    const float* W1  = (const float*)d_in[2];
    const float* as1 = (const float*)d_in[3];
    const float* ad1 = (const float*)d_in[4];
    const float* b1  = (const float*)d_in[5];
    const float* W2  = (const float*)d_in[6];
    const float* as2 = (const float*)d_in[7];
    const float* ad2 = (const float*)d_in[8];
    const float* b2  = (const float*)d_in[9];
    float* out = (float*)d_out;

    // Workspace: bf16 tables first (16B-aligned rows), then fp32, then ints.
    ushort* h1b = (ushort*)d_ws;                   // N*64 bf16
    ushort* x2b = h1b + (size_t)N_NODES * F1;      // N*64 bf16
    ushort* h2b = x2b + (size_t)N_NODES * F1;      // N*32 bf16
    float*  s1  = (float*)(h2b + (size_t)N_NODES * F2);  // N*8
    float*  d1  = s1 + (size_t)N_NODES * H1;       // N*8
    float*  s2  = d1 + (size_t)N_NODES * H1;       // N
    float*  d2  = s2 + N_NODES;                    // N
    int* cnt     = (int*)(d2 + N_NODES);           // N
    int* rank    = cnt + N_NODES;                  // N_TOT
    int* row_ptr = rank + N_TOT;                   // N+1
    int* bsum    = row_ptr + N_NODES + 1;          // 64
    int* srcs    = bsum + 64;                      // N_TOT

    hipMemsetAsync(cnt, 0, (size_t)N_NODES * sizeof(int), stream);

    const int nb_n = (N_NODES + 255) / 256;
    const int nb_w = (N_NODES * 64 + 255) / 256;   // one wave per node

    k_gemm1_hist<<<NB_G + NB_H, 256, 0, stream>>>(x, W1, as1, ad1, ei,
                                                  h1b, s1, d1, cnt, rank);
    k_scan_a<<<NCH, 256, 0, stream>>>(cnt, row_ptr, bsum);
    k_scan_b<<<1, 64, 0, stream>>>(bsum);
    k_scan_c<<<(N_NODES + 256) / 256, 256, 0, stream>>>(row_ptr, bsum);
    k_scatter<<<SLICES * NCHUNK, 256, 0, stream>>>(ei, row_ptr, rank, srcs);
    k_agg1<<<nb_w, 256, 0, stream>>>(row_ptr, srcs, h1b, s1, d1, b1, x2b);
    k_node1<<<nb_n, 256, 0, stream>>>(x2b, W2, as2, ad2, h2b, s2, d2);
    k_agg2<<<nb_w, 256, 0, stream>>>(row_ptr, srcs, h2b, s2, d2, b2, out);
}